// Round 9
// baseline (243.249 us; speedup 1.0000x reference)
//
#include <hip/hip_runtime.h>

// out[b,s,o] = sum_i x[b,s,i] * qw[o,i],  qw = ternary(W, 0.3)
// W ~ N(0, 0.1^2) => ~0.27% nonzeros => sparse signed gather-add, memory-bound.

#define TH    0.3f
#define NSLOT 12      // register-held entries per output column (covers P ~ 1-1e-5)
#define ROWS  16      // x rows staged per tile (16*512*4 = 32 KB LDS)
#define KDIM  512     // in_dim
#define NDIM  512     // out_dim

// ---------------- Kernel 1: build ternary entry table ----------------
// grid = 512 blocks (one per output row), 64 threads.
__global__ __launch_bounds__(64) void build_tbl(const float* __restrict__ w,
                                                int* __restrict__ counts,
                                                int* __restrict__ tbl) {
    const int o    = blockIdx.x;
    const int lane = threadIdx.x;
    __shared__ int c;
    __shared__ int se[KDIM];
    if (lane == 0) c = 0;
    __syncthreads();
    const float* row = w + (size_t)o * KDIM;
    for (int i = lane; i < KDIM; i += 64) {
        float v = row[i];
        if (v > TH || v < -TH) {                 // strict, matches reference
            int pos = atomicAdd(&c, 1);
            se[pos] = (i << 1) | (v < 0.0f ? 1 : 0);
        }
    }
    __syncthreads();
    const int cnt = c;
    if (lane == 0) counts[o] = cnt;
    for (int k = lane; k < NSLOT; k += 64)
        tbl[o * NSLOT + k] = (k < cnt) ? se[k] : 0;
}

// ---------------- Kernel 2: streaming sparse gather-add ----------------
// 512 threads = one per output column; grid-stride over row tiles.
__global__ __launch_bounds__(512, 8) void ternary_mm(
        const float* __restrict__ x, const float* __restrict__ w,
        const int* __restrict__ counts, const int* __restrict__ tbl,
        float* __restrict__ out, int ntiles) {
    __shared__ float4 xs4[ROWS * KDIM / 4];
    float* xs = (float*)xs4;

    const int t   = threadIdx.x;      // output column
    const int cnt = counts[t];
    int e[NSLOT];
#pragma unroll
    for (int k = 0; k < NSLOT; ++k) e[k] = tbl[t * NSLOT + k];

    for (int tile = blockIdx.x; tile < ntiles; tile += gridDim.x) {
        const size_t base = (size_t)tile * ROWS * KDIM;

        __syncthreads();   // previous tile's compute done before overwrite
        const float4* src = (const float4*)(x + base);
#pragma unroll
        for (int j = 0; j < (ROWS * KDIM / 4) / 512; ++j)
            xs4[j * 512 + t] = src[j * 512 + t];
        __syncthreads();

        if (cnt <= NSLOT) {
            // fast path: <= NSLOT nonzeros, entries in registers
#pragma unroll
            for (int r = 0; r < ROWS; ++r) {
                float acc = 0.0f;
#pragma unroll
                for (int k = 0; k < NSLOT; ++k) {
                    if (k < cnt) {
                        int   ent = e[k];
                        float v   = xs[r * KDIM + (ent >> 1)];
                        acc += (ent & 1) ? -v : v;
                    }
                }
                out[base + (size_t)r * NDIM + t] = acc;   // NDIM == KDIM
            }
        } else {
            // generic fallback (never expected): rescan weight row
            const float* wrow = w + (size_t)t * KDIM;
            for (int r = 0; r < ROWS; ++r) {
                float acc = 0.0f;
                for (int i = 0; i < KDIM; ++i) {
                    float wv = wrow[i];
                    float v  = xs[r * KDIM + i];
                    acc += (wv > TH) ? v : ((wv < -TH) ? -v : 0.0f);
                }
                out[base + (size_t)r * NDIM + t] = acc;
            }
        }
    }
}

extern "C" void kernel_launch(void* const* d_in, const int* in_sizes, int n_in,
                              void* d_out, int out_size, void* d_ws, size_t ws_size,
                              hipStream_t stream) {
    const float* x = (const float*)d_in[0];   // [16,4096,512] f32
    const float* w = (const float*)d_in[1];   // [512,512] f32
    float* out = (float*)d_out;               // [16,4096,512] f32

    int* counts = (int*)d_ws;                 // 512 ints
    int* tbl    = counts + NDIM;              // 512*NSLOT ints (~26 KB total)

    const int nrows  = in_sizes[0] / KDIM;    // 65536
    const int ntiles = nrows / ROWS;          // 4096 (exact)

    build_tbl<<<NDIM, 64, 0, stream>>>(w, counts, tbl);
    ternary_mm<<<1024, 512, 0, stream>>>(x, w, counts, tbl, out, ntiles);
}